// Round 6
// baseline (944.641 us; speedup 1.0000x reference)
//
#include <hip/hip_runtime.h>
#include <hip/hip_bf16.h>

#define EPS_BN 1e-5f

using frag8 = __attribute__((ext_vector_type(8))) short;   // 8 bf16 (4 VGPRs)
using f32x4 = __attribute__((ext_vector_type(4))) float;   // 4 fp32 acc

typedef const __attribute__((address_space(1))) void* gas_ptr;
typedef __attribute__((address_space(3))) void* las_ptr;

__device__ __forceinline__ void async_ld16(const void* g, void* l) {
  __builtin_amdgcn_global_load_lds((gas_ptr)g, (las_ptr)l, 16, 0, 0);
}

__device__ __forceinline__ float bfu2f(unsigned short u) {
  union { unsigned int i; float f; } c;
  c.i = (unsigned int)u << 16;
  return c.f;
}

// ================= small prep =================

// Wt0[f][k] = bf16(W1[k][f])   (needed before fat1's GEMM)
__global__ void wtrans1_kernel(const float* __restrict__ W1, __hip_bfloat16* __restrict__ T) {
  int i = blockIdx.x * blockDim.x + threadIdx.x;
  if (i < 512 * 128) {
    int k = i / 128, f = i % 128;
    T[f * 512 + k] = __float2bfloat16(W1[i]);
  }
}

// ================= hierarchical exclusive scan (+ dis = rsqrt(deg)) =================
__global__ void scan1_kernel(const int* __restrict__ cnt, int* __restrict__ out,
                             int* __restrict__ bsum, float* __restrict__ dis, int n) {
  __shared__ int sdata[1024];
  int tid = threadIdx.x;
  int i = blockIdx.x * 1024 + tid;
  int v = (i < n) ? cnt[i] : 0;
  if (i < n) dis[i] = rsqrtf((float)v + 1.0f);
  sdata[tid] = v;
  __syncthreads();
  for (int off = 1; off < 1024; off <<= 1) {
    int t = (tid >= off) ? sdata[tid - off] : 0;
    __syncthreads();
    sdata[tid] += t;
    __syncthreads();
  }
  if (i < n) out[i] = sdata[tid] - v;
  if (tid == 1023) bsum[blockIdx.x] = sdata[1023];
}

__global__ void scan2_kernel(int* __restrict__ bsum, int nb) {
  __shared__ int sdata[1024];
  int tid = threadIdx.x;
  int v = (tid < nb) ? bsum[tid] : 0;
  sdata[tid] = v;
  __syncthreads();
  for (int off = 1; off < 1024; off <<= 1) {
    int t = (tid >= off) ? sdata[tid - off] : 0;
    __syncthreads();
    sdata[tid] += t;
    __syncthreads();
  }
  if (tid < nb) bsum[tid] = sdata[tid] - v;
}

__global__ void scan3_kernel(int* __restrict__ out, const int* __restrict__ bsum,
                             int n, int E) {
  int i = blockIdx.x * 1024 + threadIdx.x;
  if (i < n) out[i] += bsum[blockIdx.x];
  if (i == 0) out[n] = E;
}

// ================= bf16 MFMA GEMM body: C[Nr,F] = A[Nr,K] @ Bt[F,K]^T ===========
// Pipelined: double-buffered LDS, ONE barrier per K-step.
// ASTAGE 0: A bf16 via global_load_lds
// ASTAGE 1: A fp32, VGPR staging + convert          (GEMM1 reads x directly)
// ASTAGE 2: A bf16 + BN affine from statsIn/g/beta  (GEMM3/GEMM4 fold prev BN)
// OMODE 0: bf16 out plain
// OMODE 1: bf16 out * rowscale[row]
// OMODE 3: bf16 out = relu(acc+bias[col]) + fused BN-stats accumulation
template <int TN, int ASTAGE, int OMODE>
__device__ __forceinline__ void gemm_body(
    const void* __restrict__ Ap, const __hip_bfloat16* __restrict__ Bt,
    __hip_bfloat16* __restrict__ C, const float* __restrict__ bias,
    const float* __restrict__ rowscale,
    const float* __restrict__ statsIn, const float* __restrict__ g,
    const float* __restrict__ beta, float* __restrict__ statsOut, float invN,
    int Nr, int K, int F, int bx, int by) {
  constexpr int WM = (TN == 128) ? 64 : 32;
  constexpr int MI = WM / 16;
  constexpr int BPASS = TN / 64;
  __shared__ __align__(16) __hip_bfloat16 As[2][128 * 32];
  __shared__ __align__(16) __hip_bfloat16 Bs[2][TN * 32];
  __shared__ float sacc[128], sqc[128];
  __shared__ float ssc[256], ssb[256];
  int tid = (int)threadIdx.x;
  int wid = tid >> 6, lane = tid & 63;
  int rowBase = bx * 128;
  int colBase = by * TN;
  int wr, wc;
  if (TN == 128) { wr = (wid >> 1) * 64; wc = (wid & 1) * 64; }
  else           { wr = wid * 32;        wc = 0; }

  f32x4 zero = {0.f, 0.f, 0.f, 0.f};
  f32x4 acc[MI][4];
#pragma unroll
  for (int i = 0; i < MI; ++i)
#pragma unroll
    for (int j = 0; j < 4; ++j) acc[i][j] = zero;

  int lm = lane & 15;
  int k8 = (lane >> 4) * 8;

  // ---- per-thread staging geometry (fixed across K-steps)
  int arow[2], alrow[2], akq[2], adst[2];
#pragma unroll
  for (int p = 0; p < 2; ++p) {
    int sidx = p * 256 + tid;
    alrow[p] = sidx >> 2;
    akq[p] = (sidx & 3) * 8;
    int gr = rowBase + alrow[p];
    if (gr >= Nr) gr = Nr - 1;
    arow[p] = gr;
    adst[p] = (p * 256 + wid * 64) * 16;  // byte offset (wave-uniform base for gload_lds)
  }
  int bcol[BPASS], bkq[BPASS], bdst[BPASS];
#pragma unroll
  for (int p = 0; p < BPASS; ++p) {
    int sidx = p * 256 + tid;
    bcol[p] = colBase + (sidx >> 2);
    bkq[p] = (sidx & 3) * 8;
    bdst[p] = (p * 256 + wid * 64) * 16;
  }

  if constexpr (OMODE == 3) {
    if (tid < 128) { sacc[tid] = 0.f; sqc[tid] = 0.f; }
  }
  if constexpr (ASTAGE == 2) {
    for (int k = tid; k < K; k += 256) {
      float mean = statsIn[k] * invN;
      float var = statsIn[256 + k] * invN - mean * mean;
      float sc = g[k] * rsqrtf(var + EPS_BN);
      ssc[k] = sc;
      ssb[k] = beta[k] - mean * sc;
    }
    __syncthreads();
  }

  auto cvt_store_f32 = [&](int p, int buf, float4 a, float4 b2) {
    union { frag8 f; __hip_bfloat16 h[8]; } pk;
    pk.h[0] = __float2bfloat16(a.x);  pk.h[1] = __float2bfloat16(a.y);
    pk.h[2] = __float2bfloat16(a.z);  pk.h[3] = __float2bfloat16(a.w);
    pk.h[4] = __float2bfloat16(b2.x); pk.h[5] = __float2bfloat16(b2.y);
    pk.h[6] = __float2bfloat16(b2.z); pk.h[7] = __float2bfloat16(b2.w);
    *(frag8*)&As[buf][alrow[p] * 32 + akq[p]] = pk.f;
  };
  auto cvt_store_bn = [&](int p, int buf, int kk, ushort4 a, ushort4 b2) {
    union { frag8 f; __hip_bfloat16 h[8]; } pk;
    pk.h[0] = __float2bfloat16(bfu2f(a.x)  * ssc[kk + 0] + ssb[kk + 0]);
    pk.h[1] = __float2bfloat16(bfu2f(a.y)  * ssc[kk + 1] + ssb[kk + 1]);
    pk.h[2] = __float2bfloat16(bfu2f(a.z)  * ssc[kk + 2] + ssb[kk + 2]);
    pk.h[3] = __float2bfloat16(bfu2f(a.w)  * ssc[kk + 3] + ssb[kk + 3]);
    pk.h[4] = __float2bfloat16(bfu2f(b2.x) * ssc[kk + 4] + ssb[kk + 4]);
    pk.h[5] = __float2bfloat16(bfu2f(b2.y) * ssc[kk + 5] + ssb[kk + 5]);
    pk.h[6] = __float2bfloat16(bfu2f(b2.z) * ssc[kk + 6] + ssb[kk + 6]);
    pk.h[7] = __float2bfloat16(bfu2f(b2.w) * ssc[kk + 7] + ssb[kk + 7]);
    *(frag8*)&As[buf][alrow[p] * 32 + akq[p]] = pk.f;
  };

  // ---- prologue: stage tile 0 into buffer 0
  if constexpr (ASTAGE == 0) {
#pragma unroll
    for (int p = 0; p < 2; ++p)
      async_ld16((const __hip_bfloat16*)Ap + (size_t)arow[p] * K + akq[p],
                 (char*)As[0] + adst[p]);
  } else if constexpr (ASTAGE == 1) {
#pragma unroll
    for (int p = 0; p < 2; ++p) {
      const float* s = (const float*)Ap + (size_t)arow[p] * K + akq[p];
      cvt_store_f32(p, 0, *(const float4*)s, *(const float4*)(s + 4));
    }
  } else {
#pragma unroll
    for (int p = 0; p < 2; ++p) {
      const unsigned short* s = (const unsigned short*)Ap + (size_t)arow[p] * K + akq[p];
      cvt_store_bn(p, 0, akq[p], *(const ushort4*)s, *(const ushort4*)(s + 4));
    }
  }
#pragma unroll
  for (int p = 0; p < BPASS; ++p)
    async_ld16(Bt + (size_t)bcol[p] * K + bkq[p], (char*)Bs[0] + bdst[p]);
  __syncthreads();

  int nt = K >> 5;
  int cur = 0;
  for (int t = 0; t < nt; ++t) {
    int k0n = (t + 1) << 5;
    bool hasNext = (t + 1) < nt;
    float4 pf0[2], pf1[2];
    ushort4 pu0[2], pu1[2];

    // ---- phase 1: issue next-tile loads (latency hides under MFMA)
    if (hasNext) {
      if constexpr (ASTAGE == 0) {
#pragma unroll
        for (int p = 0; p < 2; ++p)
          async_ld16((const __hip_bfloat16*)Ap + (size_t)arow[p] * K + k0n + akq[p],
                     (char*)As[cur ^ 1] + adst[p]);
      } else if constexpr (ASTAGE == 1) {
#pragma unroll
        for (int p = 0; p < 2; ++p) {
          const float* s = (const float*)Ap + (size_t)arow[p] * K + k0n + akq[p];
          pf0[p] = *(const float4*)s;
          pf1[p] = *(const float4*)(s + 4);
        }
      } else {
#pragma unroll
        for (int p = 0; p < 2; ++p) {
          const unsigned short* s =
              (const unsigned short*)Ap + (size_t)arow[p] * K + k0n + akq[p];
          pu0[p] = *(const ushort4*)s;
          pu1[p] = *(const ushort4*)(s + 4);
        }
      }
#pragma unroll
      for (int p = 0; p < BPASS; ++p)
        async_ld16(Bt + (size_t)bcol[p] * K + k0n + bkq[p], (char*)Bs[cur ^ 1] + bdst[p]);
    }

    // ---- phase 2: compute current buffer
    frag8 af[MI], bfr[4];
#pragma unroll
    for (int i = 0; i < MI; ++i)
      af[i] = *(const frag8*)&As[cur][(wr + i * 16 + lm) * 32 + k8];
#pragma unroll
    for (int j = 0; j < 4; ++j)
      bfr[j] = *(const frag8*)&Bs[cur][(wc + j * 16 + lm) * 32 + k8];
#pragma unroll
    for (int i = 0; i < MI; ++i)
#pragma unroll
      for (int j = 0; j < 4; ++j)
        acc[i][j] = __builtin_amdgcn_mfma_f32_16x16x32_bf16(af[i], bfr[j], acc[i][j], 0, 0, 0);

    // ---- phase 3: convert + ds_write prefetched A regs
    if (hasNext) {
      if constexpr (ASTAGE == 1) {
#pragma unroll
        for (int p = 0; p < 2; ++p) cvt_store_f32(p, cur ^ 1, pf0[p], pf1[p]);
      } else if constexpr (ASTAGE == 2) {
#pragma unroll
        for (int p = 0; p < 2; ++p) cvt_store_bn(p, cur ^ 1, k0n + akq[p], pu0[p], pu1[p]);
      }
    }
    __syncthreads();
    cur ^= 1;
  }

  // C/D layout: col=lane&15, row=(lane>>4)*4+reg  [verified m89]
  int rquad = (lane >> 4) * 4;
  float s[4] = {0.f, 0.f, 0.f, 0.f}, q[4] = {0.f, 0.f, 0.f, 0.f};
#pragma unroll
  for (int i = 0; i < MI; ++i) {
    int rb = rowBase + wr + i * 16 + rquad;
#pragma unroll
    for (int r = 0; r < 4; ++r) {
      int row = rb + r;
      if (row < Nr) {
        if constexpr (OMODE == 0) {
#pragma unroll
          for (int j = 0; j < 4; ++j) {
            int col = colBase + wc + j * 16 + lm;
            C[(size_t)row * F + col] = __float2bfloat16(acc[i][j][r]);
          }
        } else if constexpr (OMODE == 1) {
          float rs = rowscale[row];
#pragma unroll
          for (int j = 0; j < 4; ++j) {
            int col = colBase + wc + j * 16 + lm;
            C[(size_t)row * F + col] = __float2bfloat16(acc[i][j][r] * rs);
          }
        } else {  // OMODE 3: relu + stats, bf16 out
#pragma unroll
          for (int j = 0; j < 4; ++j) {
            int col = colBase + wc + j * 16 + lm;
            float v = acc[i][j][r] + bias[col];
            float rl = fmaxf(v, 0.f);
            C[(size_t)row * F + col] = __float2bfloat16(rl);
            s[j] += rl;
            q[j] += rl * rl;
          }
        }
      }
    }
  }

  if constexpr (OMODE == 3) {
#pragma unroll
    for (int j = 0; j < 4; ++j) {
      s[j] += __shfl_xor(s[j], 16, 64); s[j] += __shfl_xor(s[j], 32, 64);
      q[j] += __shfl_xor(q[j], 16, 64); q[j] += __shfl_xor(q[j], 32, 64);
    }
    if (lane < 16) {
#pragma unroll
      for (int j = 0; j < 4; ++j) {
        atomicAdd(&sacc[wc + j * 16 + lane], s[j]);
        atomicAdd(&sqc[wc + j * 16 + lane], q[j]);
      }
    }
    __syncthreads();
    if (tid < 128) {
      atomicAdd(&statsOut[colBase + tid], sacc[tid]);
      atomicAdd(&statsOut[256 + colBase + tid], sqc[tid]);
    }
  }
}

// ===== fat1: GEMM1 (fp32 A = x, B = Wt0) || ticket-count || wtrans(W2..W4) =====
// Fused on purpose: count blocks (atomics) overlap with GEMM blocks (MFMA) on
// the same grid — splitting them serialized on-stream and cost +45 us (round 4).
__global__ __launch_bounds__(256) void fat1_kernel(
    const float* __restrict__ x, const __hip_bfloat16* __restrict__ Wt0,
    __hip_bfloat16* __restrict__ T1, int Nn, int G1,
    const int* __restrict__ e_dst, int* __restrict__ cnt, int* __restrict__ rank,
    int E, int CB,
    const float* __restrict__ W2, const float* __restrict__ W3, const float* __restrict__ W4,
    __hip_bfloat16* __restrict__ Tw2, __hip_bfloat16* __restrict__ Tw3,
    __hip_bfloat16* __restrict__ Tw4) {
  int b = (int)blockIdx.x;
  if (b < G1) {
    gemm_body<128, 1, 0>(x, Wt0, T1, nullptr, nullptr, nullptr, nullptr, nullptr,
                         nullptr, 0.f, Nn, 512, 128, b, 0);
  } else if (b < G1 + CB) {
    int e = (b - G1) * 256 + (int)threadIdx.x;
    if (e < E) rank[e] = atomicAdd(&cnt[e_dst[e]], 1);
  } else {
    int i = (b - G1 - CB) * 256 + (int)threadIdx.x;
    const float* W; __hip_bfloat16* T; int K, F, base;
    if (i < 32768)       { W = W2; T = Tw2; K = 128; F = 256; base = 0; }
    else if (i < 65536)  { W = W3; T = Tw3; K = 256; F = 128; base = 32768; }
    else if (i < 73728)  { W = W4; T = Tw4; K = 128; F = 64;  base = 65536; }
    else return;
    int j = i - base;
    int k = j / F, f = j % F;
    T[f * K + k] = __float2bfloat16(W[j]);
  }
}

template <int TN, int ASTAGE, int OMODE>
__global__ __launch_bounds__(256) void mfma_gemm_kernel(
    const void* __restrict__ A, const __hip_bfloat16* __restrict__ Bt,
    __hip_bfloat16* __restrict__ C, const float* __restrict__ bias,
    const float* __restrict__ rowscale, const float* __restrict__ statsIn,
    const float* __restrict__ g, const float* __restrict__ beta,
    float* __restrict__ statsOut, float invN, int Nr, int K, int F) {
  gemm_body<TN, ASTAGE, OMODE>(A, Bt, C, bias, rowscale, statsIn, g, beta, statsOut,
                               invN, Nr, K, F, (int)blockIdx.x, (int)blockIdx.y);
}

// ===== fat2: atomic-free scatter (rescale of T1 folded into agg L1) =====
__global__ __launch_bounds__(256) void fat2_kernel(
    const int* __restrict__ src, const int* __restrict__ dst,
    const int* __restrict__ rowstart, const int* __restrict__ rank,
    int* __restrict__ csr_src, int E) {
  int e = (int)blockIdx.x * 256 + (int)threadIdx.x;
  if (e < E) csr_src[rowstart[dst[e]] + rank[e]] = src[e];
}

// ================= aggregation (persistent grid-stride) =================
// TWO destination rows per wave, gather batches interleaved -> 32 row-gathers
// in flight (was 16). Index/dis fetch: one load by 16-lane group + __shfl.
// AMODE 1 (L1): input UNSCALED T1; scale gathered rows by dis[src]; self by
//               dis[d]. H=dis*acc+bias; stats; R=bf16(relu(H)*dis); sd[d]
// AMODE 2 (L2 pre): input pre-scaled; out = bf16(dis*(ssc[c]*acc + ssb[c]*sd[d]))
// AMODE 3 (L3): input pre-scaled; H=dis*acc+bias; stats; R = bf16(relu(H))
// AMODE 4 (L4): input pre-scaled; H=dis*acc+bias; stats; R = fp32 relu(H)
template <int VEC, int AMODE>
__global__ __launch_bounds__(256) void agg_kernel(
    const __hip_bfloat16* __restrict__ Ts, const int* __restrict__ rowstart,
    const int* __restrict__ csr_src, const float* __restrict__ dis,
    const float* __restrict__ bias, void* __restrict__ H,
    float* __restrict__ stats, const float* __restrict__ statsIn,
    const float* __restrict__ g, const float* __restrict__ beta,
    float* __restrict__ sd, float invN, int Nn, int F) {
  __shared__ float lsum[512], lqs[512];
  __shared__ float ssc[128], ssb[128];
  int tid = (int)threadIdx.x;
  int wid4 = tid >> 6;
  int lane = tid & 63;
  int off = lane * VEC;
  const unsigned short* Tu = (const unsigned short*)Ts;

  if constexpr (AMODE == 2) {
    if (tid < F) {
      float mean = statsIn[tid] * invN;
      float var = statsIn[256 + tid] * invN - mean * mean;
      float sc = g[tid] * rsqrtf(var + EPS_BN);
      ssc[tid] = sc;
      ssb[tid] = beta[tid] - mean * sc;
    }
    __syncthreads();
  }

  float bj[VEC];
  float s[VEC], q[VEC];
#pragma unroll
  for (int j = 0; j < VEC; ++j) {
    bj[j] = (AMODE == 1 || AMODE == 3 || AMODE == 4) ? bias[off + j] : 0.f;
    s[j] = 0.f; q[j] = 0.f;
  }

  int l16 = lane & 15;

  for (int dbase = (blockIdx.x * 4 + wid4) * 2; dbase < Nn; dbase += gridDim.x * 8) {
    int d0 = dbase;
    int d1 = dbase + 1;
    bool has1 = d1 < Nn;
    float dd0 = dis[d0];
    float dd1 = has1 ? dis[d1] : 1.f;
    float acc0[VEC], acc1[VEC];
    {  // self terms
      unsigned short r[VEC];
      if constexpr (VEC == 2) *(ushort2*)r = *(const ushort2*)&Tu[(size_t)d0 * F + off];
      else                    r[0] = Tu[(size_t)d0 * F + off];
#pragma unroll
      for (int j = 0; j < VEC; ++j)
        acc0[j] = (AMODE == 1) ? bfu2f(r[j]) * dd0 : bfu2f(r[j]);
      if (has1) {
        if constexpr (VEC == 2) *(ushort2*)r = *(const ushort2*)&Tu[(size_t)d1 * F + off];
        else                    r[0] = Tu[(size_t)d1 * F + off];
#pragma unroll
        for (int j = 0; j < VEC; ++j)
          acc1[j] = (AMODE == 1) ? bfu2f(r[j]) * dd1 : bfu2f(r[j]);
      } else {
#pragma unroll
        for (int j = 0; j < VEC; ++j) acc1[j] = 0.f;
      }
    }
    float sda0 = dd0, sda1 = dd1;

    int rs0 = rowstart[d0];
    int re0 = rowstart[d0 + 1];
    int re1 = has1 ? rowstart[d1 + 1] : re0;
    int n0 = re0 - rs0;
    int rs1 = re0;  // CSR contiguity
    int n1 = re1 - rs1;
    int nb = n0 > n1 ? n0 : n1;

    for (int b = 0; b < nb; b += 16) {
      // cooperative index fetch for both rows (clamped; masked at accumulate)
      int ee0 = rs0 + b + l16; if (ee0 >= re0) ee0 = re0 - 1; if (n0 <= 0) ee0 = 0;
      int ee1 = rs1 + b + l16; if (ee1 >= re1) ee1 = re1 - 1; if (n1 <= 0) ee1 = 0;
      int my0 = csr_src[ee0];
      int my1 = csr_src[ee1];
      float md0 = 0.f, md1 = 0.f;
      if constexpr (AMODE == 1) { md0 = dis[my0]; md1 = dis[my1]; }
      int idx0[16], idx1[16];
      float dv0[16], dv1[16];
#pragma unroll
      for (int p = 0; p < 16; ++p) {
        idx0[p] = __shfl(my0, p, 16);
        idx1[p] = __shfl(my1, p, 16);
        if constexpr (AMODE == 1) {
          dv0[p] = __shfl(md0, p, 16);
          dv1[p] = __shfl(md1, p, 16);
        }
      }
      unsigned short r0[16][VEC], r1[16][VEC];
#pragma unroll
      for (int p = 0; p < 16; ++p) {
        if constexpr (VEC == 2) *(ushort2*)r0[p] = *(const ushort2*)&Tu[(size_t)idx0[p] * F + off];
        else                    r0[p][0] = Tu[(size_t)idx0[p] * F + off];
      }
#pragma unroll
      for (int p = 0; p < 16; ++p) {
        if constexpr (VEC == 2) *(ushort2*)r1[p] = *(const ushort2*)&Tu[(size_t)idx1[p] * F + off];
        else                    r1[p][0] = Tu[(size_t)idx1[p] * F + off];
      }
#pragma unroll
      for (int p = 0; p < 16; ++p) {
        bool v0 = (b + p) < n0;
        bool v1 = (b + p) < n1;
        if constexpr (AMODE == 1) {
#pragma unroll
          for (int j = 0; j < VEC; ++j) {
            acc0[j] += v0 ? bfu2f(r0[p][j]) * dv0[p] : 0.f;
            acc1[j] += v1 ? bfu2f(r1[p][j]) * dv1[p] : 0.f;
          }
          sda0 += v0 ? dv0[p] : 0.f;
          sda1 += v1 ? dv1[p] : 0.f;
        } else {
#pragma unroll
          for (int j = 0; j < VEC; ++j) {
            acc0[j] += v0 ? bfu2f(r0[p][j]) : 0.f;
            acc1[j] += v1 ? bfu2f(r1[p][j]) : 0.f;
          }
        }
      }
    }

    // ---- epilogue row 0
    if constexpr (AMODE == 2) {
      float sdv = sd[d0];
      union { ushort2 u; __hip_bfloat16 h[2]; } pk;
      pk.h[0] = __float2bfloat16(dd0 * (ssc[off + 0] * acc0[0] + ssb[off + 0] * sdv));
      pk.h[1] = __float2bfloat16(dd0 * (ssc[off + 1] * acc0[1] + ssb[off + 1] * sdv));
      *(ushort2*)&((__hip_bfloat16*)H)[(size_t)d0 * F + off] = pk.u;
    } else {
      float rl[VEC];
#pragma unroll
      for (int j = 0; j < VEC; ++j) {
        float v = acc0[j] * dd0 + bj[j];
        rl[j] = fmaxf(v, 0.f);
        s[j] += rl[j];
        q[j] += rl[j] * rl[j];
      }
      if constexpr (AMODE == 1) {
        union { ushort2 u; __hip_bfloat16 h[2]; } pk;
        pk.h[0] = __float2bfloat16(rl[0] * dd0);
        pk.h[1] = __float2bfloat16(rl[1] * dd0);
        *(ushort2*)&((__hip_bfloat16*)H)[(size_t)d0 * F + off] = pk.u;
        if (lane == 0) sd[d0] = sda0;
      } else if constexpr (AMODE == 3) {
        union { ushort2 u; __hip_bfloat16 h[2]; } pk;
        pk.h[0] = __float2bfloat16(rl[0]);
        pk.h[1] = __float2bfloat16(rl[1]);
        *(ushort2*)&((__hip_bfloat16*)H)[(size_t)d0 * F + off] = pk.u;
      } else {
        ((float*)H)[(size_t)d0 * F + off] = rl[0];
      }
    }
    // ---- epilogue row 1
    if (has1) {
      if constexpr (AMODE == 2) {
        float sdv = sd[d1];
        union { ushort2 u; __hip_bfloat16 h[2]; } pk;
        pk.h[0] = __float2bfloat16(dd1 * (ssc[off + 0] * acc1[0] + ssb[off + 0] * sdv));
        pk.h[1] = __float2bfloat16(dd1 * (ssc[off + 1] * acc1[1] + ssb[off + 1] * sdv));
        *(ushort2*)&((__hip_bfloat16*)H)[(size_t)d1 * F + off] = pk.u;
      } else {
        float rl[VEC];
#pragma unroll
        for (int j = 0; j < VEC; ++j) {
          float v = acc1[j] * dd1 + bj[j];
          rl[j] = fmaxf(v, 0.f);
          s[j] += rl[j];
          q[j] += rl[j] * rl[j];
        }
        if constexpr (AMODE == 1) {
          union { ushort2 u; __hip_bfloat16 h[2]; } pk;
          pk.h[0] = __float2bfloat16(rl[0] * dd1);
          pk.h[1] = __float2bfloat16(rl[1] * dd1);
          *(ushort2*)&((__hip_bfloat16*)H)[(size_t)d1 * F + off] = pk.u;
          if (lane == 0) sd[d1] = sda1;
        } else if constexpr (AMODE == 3) {
          union { ushort2 u; __hip_bfloat16 h[2]; } pk;
          pk.h[0] = __float2bfloat16(rl[0]);
          pk.h[1] = __float2bfloat16(rl[1]);
          *(ushort2*)&((__hip_bfloat16*)H)[(size_t)d1 * F + off] = pk.u;
        } else {
          ((float*)H)[(size_t)d1 * F + off] = rl[0];
        }
      }
    }
  }

  if constexpr (AMODE != 2) {
#pragma unroll
    for (int j = 0; j < VEC; ++j) {
      lsum[(lane * VEC + j) * 4 + wid4] = s[j];
      lqs[(lane * VEC + j) * 4 + wid4] = q[j];
    }
    __syncthreads();
    int nc = 64 * VEC;  // == F
    for (int c = tid; c < nc; c += 256) {
      float a = lsum[c * 4 + 0] + lsum[c * 4 + 1] + lsum[c * 4 + 2] + lsum[c * 4 + 3];
      float b = lqs[c * 4 + 0] + lqs[c * 4 + 1] + lqs[c * 4 + 2] + lqs[c * 4 + 3];
      atomicAdd(&stats[c], a);
      atomicAdd(&stats[256 + c], b);
    }
  }
}

// ================= fused L4 BN-apply + classifier =================
// input R4 already relu'd (fp32); one wave per row.
__global__ __launch_bounds__(256) void bnapply_cls_kernel(
    const float* __restrict__ R4, const float* __restrict__ stats,
    const float* __restrict__ g, const float* __restrict__ beta,
    const float* __restrict__ Wc, const float* __restrict__ bc,
    float* __restrict__ out, int Nn, float invN) {
  __shared__ float ssc[64], ssb[64];
  int tid = (int)threadIdx.x;
  if (tid < 64) {
    float mean = stats[tid] * invN;
    float var = stats[256 + tid] * invN - mean * mean;
    float sc = g[tid] * rsqrtf(var + EPS_BN);
    ssc[tid] = sc;
    ssb[tid] = beta[tid] - mean * sc;
  }
  __syncthreads();
  int gt = blockIdx.x * blockDim.x + tid;
  int wid = gt >> 6;
  int lane = tid & 63;
  if (wid >= Nn) return;
  float v = R4[(size_t)wid * 64 + lane];
  float h = v * ssc[lane] + ssb[lane];
#pragma unroll
  for (int c = 0; c < 10; ++c) {
    float p = h * Wc[lane * 10 + c];
#pragma unroll
    for (int off = 32; off > 0; off >>= 1) p += __shfl_down(p, off, 64);
    if (lane == 0) out[(size_t)wid * 10 + c] = p + bc[c];
  }
}

// ================= host launch =================

extern "C" void kernel_launch(void* const* d_in, const int* in_sizes, int n_in,
                              void* d_out, int out_size, void* d_ws, size_t ws_size,
                              hipStream_t stream) {
  (void)n_in; (void)out_size; (void)ws_size;
  const float* x    = (const float*)d_in[0];
  const int*   edge = (const int*)d_in[1];
  const int E  = in_sizes[1] / 2;
  const int Nn = in_sizes[0] / 512;
  const int* e_src = edge;
  const int* e_dst = edge + E;

  const float* W[4]  = {(const float*)d_in[2],  (const float*)d_in[6],
                        (const float*)d_in[10], (const float*)d_in[14]};
  const float* bv[4] = {(const float*)d_in[3],  (const float*)d_in[7],
                        (const float*)d_in[11], (const float*)d_in[15]};
  const float* gv[4] = {(const float*)d_in[4],  (const float*)d_in[8],
                        (const float*)d_in[12], (const float*)d_in[16]};
  const float* bt[4] = {(const float*)d_in[5],  (const float*)d_in[9],
                        (const float*)d_in[13], (const float*)d_in[17]};
  const float* Wc = (const float*)d_in[18];
  const float* bc = (const float*)d_in[19];
  float* out = (float*)d_out;

  const float invN = 1.0f / (float)Nn;

  char* p = (char*)d_ws;
  auto alloc = [&](size_t bytes) -> void* {
    void* r = (void*)p;
    p += (bytes + 255) & ~(size_t)255;
    return r;
  };
  // cnt + stats adjacent -> single memset covers both
  int*   cnt      = (int*)alloc((size_t)Nn * 4);
  float* stats    = (float*)alloc(2048 * 4);   // L1 | L2 | L3 | L4, each 512
  size_t zeroBytes = (size_t)(((size_t)Nn * 4 + 255) & ~(size_t)255) + 2048 * 4;
  int*   rowstart = (int*)alloc((size_t)(Nn + 1) * 4);
  int*   bsum     = (int*)alloc(1024 * 4);
  float* dis      = (float*)alloc((size_t)Nn * 4);
  float* sd       = (float*)alloc((size_t)Nn * 4);
  int*   rank     = (int*)alloc((size_t)E * 4);
  int*   csr_src  = (int*)alloc((size_t)E * 4);
  __hip_bfloat16* Wt0 = (__hip_bfloat16*)alloc(512 * 128 * 2);
  __hip_bfloat16* Wt1 = (__hip_bfloat16*)alloc(128 * 256 * 2);
  __hip_bfloat16* Wt2 = (__hip_bfloat16*)alloc(256 * 128 * 2);
  __hip_bfloat16* Wt3 = (__hip_bfloat16*)alloc(128 * 64 * 2);
  __hip_bfloat16* Ts1 = (__hip_bfloat16*)alloc((size_t)Nn * 128 * 2);
  __hip_bfloat16* R1  = (__hip_bfloat16*)alloc((size_t)Nn * 128 * 2);
  __hip_bfloat16* Tb2 = (__hip_bfloat16*)alloc((size_t)Nn * 128 * 2);
  __hip_bfloat16* R2  = (__hip_bfloat16*)alloc((size_t)Nn * 256 * 2);
  __hip_bfloat16* Ts3 = (__hip_bfloat16*)alloc((size_t)Nn * 128 * 2);
  __hip_bfloat16* R3  = (__hip_bfloat16*)alloc((size_t)Nn * 128 * 2);
  __hip_bfloat16* Ts4 = (__hip_bfloat16*)alloc((size_t)Nn * 64 * 2);
  float*          R4  = (float*)alloc((size_t)Nn * 64 * 4);

  hipMemsetAsync(cnt, 0, zeroBytes, stream);

  // Wt0 first (fat1's GEMM B operand)
  wtrans1_kernel<<<(512 * 128 + 255) / 256, 256, 0, stream>>>(W[0], Wt0);

  // ---- fat1: GEMM1 (x fp32 -> Ts1 bf16, unscaled) || ticket count || wtrans W2..W4
  const int gx = (Nn + 127) / 128;
  const int CB = (E + 255) / 256;
  const int WB = (73728 + 255) / 256;
  fat1_kernel<<<gx + CB + WB, 256, 0, stream>>>(
      x, Wt0, Ts1, Nn, gx, e_dst, cnt, rank, E, CB,
      W[1], W[2], W[3], Wt1, Wt2, Wt3);

  int nb = (Nn + 1023) / 1024;
  scan1_kernel<<<nb, 1024, 0, stream>>>(cnt, rowstart, bsum, dis, Nn);
  scan2_kernel<<<1, 1024, 0, stream>>>(bsum, nb);
  scan3_kernel<<<nb, 1024, 0, stream>>>(rowstart, bsum, Nn, E);

  // ---- fat2: scatter only (T1 stays unscaled; agg L1 folds dis)
  fat2_kernel<<<CB, 256, 0, stream>>>(e_src, e_dst, rowstart, rank, csr_src, E);

  const int AGG_BLOCKS = 2048;

  // ---- L1: agg(T1 unscaled) -> R1 = relu(H1)*dis bf16, stats0, sd
  agg_kernel<2, 1><<<AGG_BLOCKS, 256, 0, stream>>>(
      Ts1, rowstart, csr_src, dis, bv[0], R1, stats, nullptr, nullptr, nullptr,
      sd, invN, Nn, 128);
  // ---- L2 pre-agg: agg(R1) -> Tb2 (BN1 folded)
  agg_kernel<2, 2><<<AGG_BLOCKS, 256, 0, stream>>>(
      R1, rowstart, csr_src, dis, nullptr, Tb2, nullptr, stats, gv[0], bt[0],
      sd, invN, Nn, 128);
  // ---- GEMM2: Tb2[128] -> R2 = relu(H2) bf16 [256], stats1
  {
    dim3 g(gx, 2);
    mfma_gemm_kernel<128, 0, 3><<<g, 256, 0, stream>>>(
        Tb2, Wt1, R2, bv[1], nullptr, nullptr, nullptr, nullptr, stats + 512, invN,
        Nn, 128, 256);
  }
  // ---- GEMM3: A = BN2(R2) via affine staging -> Ts3 = out*dis bf16 [128]
  {
    dim3 g(gx, 1);
    mfma_gemm_kernel<128, 2, 1><<<g, 256, 0, stream>>>(
        R2, Wt2, Ts3, nullptr, dis, stats + 512, gv[1], bt[1], nullptr, invN,
        Nn, 256, 128);
  }
  // ---- L3: agg(Ts3) -> R3 = relu(H3) bf16, stats2
  agg_kernel<2, 3><<<AGG_BLOCKS, 256, 0, stream>>>(
      Ts3, rowstart, csr_src, dis, bv[2], R3, stats + 1024, nullptr, nullptr, nullptr,
      nullptr, invN, Nn, 128);
  // ---- GEMM4: A = BN3(R3) via affine staging -> Ts4 = out*dis bf16 [64]
  {
    dim3 g(gx, 1);
    mfma_gemm_kernel<64, 2, 1><<<g, 256, 0, stream>>>(
        R3, Wt3, Ts4, nullptr, dis, stats + 1024, gv[2], bt[2], nullptr, invN,
        Nn, 128, 64);
  }
  // ---- L4: agg(Ts4) -> R4 = relu(H4) fp32, stats3
  agg_kernel<1, 4><<<AGG_BLOCKS, 256, 0, stream>>>(
      Ts4, rowstart, csr_src, dis, bv[3], R4, stats + 1536, nullptr, nullptr, nullptr,
      nullptr, invN, Nn, 64);
  // ---- BN4 + classifier
  int clsBlocks = (Nn * 64 + 255) / 256;
  bnapply_cls_kernel<<<clsBlocks, 256, 0, stream>>>(R4, stats + 1536, gv[3], bt[3],
                                                    Wc, bc, out, Nn, invN);
}

// Round 7
// 933.135 us; speedup vs baseline: 1.0123x; 1.0123x over previous
//
#include <hip/hip_runtime.h>
#include <hip/hip_bf16.h>

#define EPS_BN 1e-5f

using frag8 = __attribute__((ext_vector_type(8))) short;   // 8 bf16 (4 VGPRs)
using f32x4 = __attribute__((ext_vector_type(4))) float;   // 4 fp32 acc

typedef const __attribute__((address_space(1))) void* gas_ptr;
typedef __attribute__((address_space(3))) void* las_ptr;

__device__ __forceinline__ void async_ld16(const void* g, void* l) {
  __builtin_amdgcn_global_load_lds((gas_ptr)g, (las_ptr)l, 16, 0, 0);
}

__device__ __forceinline__ float bfu2f(unsigned short u) {
  union { unsigned int i; float f; } c;
  c.i = (unsigned int)u << 16;
  return c.f;
}

// ================= small prep =================

// Wt0[f][k] = bf16(W1[k][f])   (needed before fat1's GEMM)
__global__ void wtrans1_kernel(const float* __restrict__ W1, __hip_bfloat16* __restrict__ T) {
  int i = blockIdx.x * blockDim.x + threadIdx.x;
  if (i < 512 * 128) {
    int k = i / 128, f = i % 128;
    T[f * 512 + k] = __float2bfloat16(W1[i]);
  }
}

// ================= hierarchical exclusive scan (+ dis = rsqrt(deg)) =================
__global__ void scan1_kernel(const int* __restrict__ cnt, int* __restrict__ out,
                             int* __restrict__ bsum, float* __restrict__ dis, int n) {
  __shared__ int sdata[1024];
  int tid = threadIdx.x;
  int i = blockIdx.x * 1024 + tid;
  int v = (i < n) ? cnt[i] : 0;
  if (i < n) dis[i] = rsqrtf((float)v + 1.0f);
  sdata[tid] = v;
  __syncthreads();
  for (int off = 1; off < 1024; off <<= 1) {
    int t = (tid >= off) ? sdata[tid - off] : 0;
    __syncthreads();
    sdata[tid] += t;
    __syncthreads();
  }
  if (i < n) out[i] = sdata[tid] - v;
  if (tid == 1023) bsum[blockIdx.x] = sdata[1023];
}

__global__ void scan2_kernel(int* __restrict__ bsum, int nb) {
  __shared__ int sdata[1024];
  int tid = threadIdx.x;
  int v = (tid < nb) ? bsum[tid] : 0;
  sdata[tid] = v;
  __syncthreads();
  for (int off = 1; off < 1024; off <<= 1) {
    int t = (tid >= off) ? sdata[tid - off] : 0;
    __syncthreads();
    sdata[tid] += t;
    __syncthreads();
  }
  if (tid < nb) bsum[tid] = sdata[tid] - v;
}

__global__ void scan3_kernel(int* __restrict__ out, const int* __restrict__ bsum,
                             int n, int E) {
  int i = blockIdx.x * 1024 + threadIdx.x;
  if (i < n) out[i] += bsum[blockIdx.x];
  if (i == 0) out[n] = E;
}

// ================= bf16 MFMA GEMM body: C[Nr,F] = A[Nr,K] @ Bt[F,K]^T ===========
// Pipelined: double-buffered LDS, ONE barrier per K-step.
// ASTAGE 0: A bf16 via global_load_lds
// ASTAGE 1: A fp32, VGPR staging + convert          (GEMM1 reads x directly)
// ASTAGE 2: A bf16 + BN affine from statsIn/g/beta  (GEMM3/GEMM4 fold prev BN)
// OMODE 0: bf16 out plain
// OMODE 1: bf16 out * rowscale[row]
// OMODE 3: bf16 out = relu(acc+bias[col]) + fused BN-stats accumulation
template <int TN, int ASTAGE, int OMODE>
__device__ __forceinline__ void gemm_body(
    const void* __restrict__ Ap, const __hip_bfloat16* __restrict__ Bt,
    __hip_bfloat16* __restrict__ C, const float* __restrict__ bias,
    const float* __restrict__ rowscale,
    const float* __restrict__ statsIn, const float* __restrict__ g,
    const float* __restrict__ beta, float* __restrict__ statsOut, float invN,
    int Nr, int K, int F, int bx, int by) {
  constexpr int WM = (TN == 128) ? 64 : 32;
  constexpr int MI = WM / 16;
  constexpr int BPASS = TN / 64;
  __shared__ __align__(16) __hip_bfloat16 As[2][128 * 32];
  __shared__ __align__(16) __hip_bfloat16 Bs[2][TN * 32];
  __shared__ float sacc[128], sqc[128];
  __shared__ float ssc[256], ssb[256];
  int tid = (int)threadIdx.x;
  int wid = tid >> 6, lane = tid & 63;
  int rowBase = bx * 128;
  int colBase = by * TN;
  int wr, wc;
  if (TN == 128) { wr = (wid >> 1) * 64; wc = (wid & 1) * 64; }
  else           { wr = wid * 32;        wc = 0; }

  f32x4 zero = {0.f, 0.f, 0.f, 0.f};
  f32x4 acc[MI][4];
#pragma unroll
  for (int i = 0; i < MI; ++i)
#pragma unroll
    for (int j = 0; j < 4; ++j) acc[i][j] = zero;

  int lm = lane & 15;
  int k8 = (lane >> 4) * 8;

  // ---- per-thread staging geometry (fixed across K-steps)
  int arow[2], alrow[2], akq[2], adst[2];
#pragma unroll
  for (int p = 0; p < 2; ++p) {
    int sidx = p * 256 + tid;
    alrow[p] = sidx >> 2;
    akq[p] = (sidx & 3) * 8;
    int gr = rowBase + alrow[p];
    if (gr >= Nr) gr = Nr - 1;
    arow[p] = gr;
    adst[p] = (p * 256 + wid * 64) * 16;  // byte offset (wave-uniform base for gload_lds)
  }
  int bcol[BPASS], bkq[BPASS], bdst[BPASS];
#pragma unroll
  for (int p = 0; p < BPASS; ++p) {
    int sidx = p * 256 + tid;
    bcol[p] = colBase + (sidx >> 2);
    bkq[p] = (sidx & 3) * 8;
    bdst[p] = (p * 256 + wid * 64) * 16;
  }

  if constexpr (OMODE == 3) {
    if (tid < 128) { sacc[tid] = 0.f; sqc[tid] = 0.f; }
  }
  if constexpr (ASTAGE == 2) {
    for (int k = tid; k < K; k += 256) {
      float mean = statsIn[k] * invN;
      float var = statsIn[256 + k] * invN - mean * mean;
      float sc = g[k] * rsqrtf(var + EPS_BN);
      ssc[k] = sc;
      ssb[k] = beta[k] - mean * sc;
    }
    __syncthreads();
  }

  auto cvt_store_f32 = [&](int p, int buf, float4 a, float4 b2) {
    union { frag8 f; __hip_bfloat16 h[8]; } pk;
    pk.h[0] = __float2bfloat16(a.x);  pk.h[1] = __float2bfloat16(a.y);
    pk.h[2] = __float2bfloat16(a.z);  pk.h[3] = __float2bfloat16(a.w);
    pk.h[4] = __float2bfloat16(b2.x); pk.h[5] = __float2bfloat16(b2.y);
    pk.h[6] = __float2bfloat16(b2.z); pk.h[7] = __float2bfloat16(b2.w);
    *(frag8*)&As[buf][alrow[p] * 32 + akq[p]] = pk.f;
  };
  auto cvt_store_bn = [&](int p, int buf, int kk, ushort4 a, ushort4 b2) {
    union { frag8 f; __hip_bfloat16 h[8]; } pk;
    pk.h[0] = __float2bfloat16(bfu2f(a.x)  * ssc[kk + 0] + ssb[kk + 0]);
    pk.h[1] = __float2bfloat16(bfu2f(a.y)  * ssc[kk + 1] + ssb[kk + 1]);
    pk.h[2] = __float2bfloat16(bfu2f(a.z)  * ssc[kk + 2] + ssb[kk + 2]);
    pk.h[3] = __float2bfloat16(bfu2f(a.w)  * ssc[kk + 3] + ssb[kk + 3]);
    pk.h[4] = __float2bfloat16(bfu2f(b2.x) * ssc[kk + 4] + ssb[kk + 4]);
    pk.h[5] = __float2bfloat16(bfu2f(b2.y) * ssc[kk + 5] + ssb[kk + 5]);
    pk.h[6] = __float2bfloat16(bfu2f(b2.z) * ssc[kk + 6] + ssb[kk + 6]);
    pk.h[7] = __float2bfloat16(bfu2f(b2.w) * ssc[kk + 7] + ssb[kk + 7]);
    *(frag8*)&As[buf][alrow[p] * 32 + akq[p]] = pk.f;
  };

  // ---- prologue: stage tile 0 into buffer 0
  if constexpr (ASTAGE == 0) {
#pragma unroll
    for (int p = 0; p < 2; ++p)
      async_ld16((const __hip_bfloat16*)Ap + (size_t)arow[p] * K + akq[p],
                 (char*)As[0] + adst[p]);
  } else if constexpr (ASTAGE == 1) {
#pragma unroll
    for (int p = 0; p < 2; ++p) {
      const float* s = (const float*)Ap + (size_t)arow[p] * K + akq[p];
      cvt_store_f32(p, 0, *(const float4*)s, *(const float4*)(s + 4));
    }
  } else {
#pragma unroll
    for (int p = 0; p < 2; ++p) {
      const unsigned short* s = (const unsigned short*)Ap + (size_t)arow[p] * K + akq[p];
      cvt_store_bn(p, 0, akq[p], *(const ushort4*)s, *(const ushort4*)(s + 4));
    }
  }
#pragma unroll
  for (int p = 0; p < BPASS; ++p)
    async_ld16(Bt + (size_t)bcol[p] * K + bkq[p], (char*)Bs[0] + bdst[p]);
  __syncthreads();

  int nt = K >> 5;
  int cur = 0;
  for (int t = 0; t < nt; ++t) {
    int k0n = (t + 1) << 5;
    bool hasNext = (t + 1) < nt;
    float4 pf0[2], pf1[2];
    ushort4 pu0[2], pu1[2];

    // ---- phase 1: issue next-tile loads (latency hides under MFMA)
    if (hasNext) {
      if constexpr (ASTAGE == 0) {
#pragma unroll
        for (int p = 0; p < 2; ++p)
          async_ld16((const __hip_bfloat16*)Ap + (size_t)arow[p] * K + k0n + akq[p],
                     (char*)As[cur ^ 1] + adst[p]);
      } else if constexpr (ASTAGE == 1) {
#pragma unroll
        for (int p = 0; p < 2; ++p) {
          const float* s = (const float*)Ap + (size_t)arow[p] * K + k0n + akq[p];
          pf0[p] = *(const float4*)s;
          pf1[p] = *(const float4*)(s + 4);
        }
      } else {
#pragma unroll
        for (int p = 0; p < 2; ++p) {
          const unsigned short* s =
              (const unsigned short*)Ap + (size_t)arow[p] * K + k0n + akq[p];
          pu0[p] = *(const ushort4*)s;
          pu1[p] = *(const ushort4*)(s + 4);
        }
      }
#pragma unroll
      for (int p = 0; p < BPASS; ++p)
        async_ld16(Bt + (size_t)bcol[p] * K + k0n + bkq[p], (char*)Bs[cur ^ 1] + bdst[p]);
    }

    // ---- phase 2: compute current buffer
    frag8 af[MI], bfr[4];
#pragma unroll
    for (int i = 0; i < MI; ++i)
      af[i] = *(const frag8*)&As[cur][(wr + i * 16 + lm) * 32 + k8];
#pragma unroll
    for (int j = 0; j < 4; ++j)
      bfr[j] = *(const frag8*)&Bs[cur][(wc + j * 16 + lm) * 32 + k8];
#pragma unroll
    for (int i = 0; i < MI; ++i)
#pragma unroll
      for (int j = 0; j < 4; ++j)
        acc[i][j] = __builtin_amdgcn_mfma_f32_16x16x32_bf16(af[i], bfr[j], acc[i][j], 0, 0, 0);

    // ---- phase 3: convert + ds_write prefetched A regs
    if (hasNext) {
      if constexpr (ASTAGE == 1) {
#pragma unroll
        for (int p = 0; p < 2; ++p) cvt_store_f32(p, cur ^ 1, pf0[p], pf1[p]);
      } else if constexpr (ASTAGE == 2) {
#pragma unroll
        for (int p = 0; p < 2; ++p) cvt_store_bn(p, cur ^ 1, k0n + akq[p], pu0[p], pu1[p]);
      }
    }
    __syncthreads();
    cur ^= 1;
  }

  // C/D layout: col=lane&15, row=(lane>>4)*4+reg  [verified m89]
  int rquad = (lane >> 4) * 4;
  float s[4] = {0.f, 0.f, 0.f, 0.f}, q[4] = {0.f, 0.f, 0.f, 0.f};
#pragma unroll
  for (int i = 0; i < MI; ++i) {
    int rb = rowBase + wr + i * 16 + rquad;
#pragma unroll
    for (int r = 0; r < 4; ++r) {
      int row = rb + r;
      if (row < Nr) {
        if constexpr (OMODE == 0) {
#pragma unroll
          for (int j = 0; j < 4; ++j) {
            int col = colBase + wc + j * 16 + lm;
            C[(size_t)row * F + col] = __float2bfloat16(acc[i][j][r]);
          }
        } else if constexpr (OMODE == 1) {
          float rs = rowscale[row];
#pragma unroll
          for (int j = 0; j < 4; ++j) {
            int col = colBase + wc + j * 16 + lm;
            C[(size_t)row * F + col] = __float2bfloat16(acc[i][j][r] * rs);
          }
        } else {  // OMODE 3: relu + stats, bf16 out
#pragma unroll
          for (int j = 0; j < 4; ++j) {
            int col = colBase + wc + j * 16 + lm;
            float v = acc[i][j][r] + bias[col];
            float rl = fmaxf(v, 0.f);
            C[(size_t)row * F + col] = __float2bfloat16(rl);
            s[j] += rl;
            q[j] += rl * rl;
          }
        }
      }
    }
  }

  if constexpr (OMODE == 3) {
#pragma unroll
    for (int j = 0; j < 4; ++j) {
      s[j] += __shfl_xor(s[j], 16, 64); s[j] += __shfl_xor(s[j], 32, 64);
      q[j] += __shfl_xor(q[j], 16, 64); q[j] += __shfl_xor(q[j], 32, 64);
    }
    if (lane < 16) {
#pragma unroll
      for (int j = 0; j < 4; ++j) {
        atomicAdd(&sacc[wc + j * 16 + lane], s[j]);
        atomicAdd(&sqc[wc + j * 16 + lane], q[j]);
      }
    }
    __syncthreads();
    if (tid < 128) {
      atomicAdd(&statsOut[colBase + tid], sacc[tid]);
      atomicAdd(&statsOut[256 + colBase + tid], sqc[tid]);
    }
  }
}

// ===== fat1: GEMM1 || ticket-count || wtrans(W2..W4), roles INTERLEAVED =====
// Every S-th block is a GEMM block so count blocks are co-resident with GEMM
// blocks from dispatch start (range-partitioned roles left the 6250 atomic
// blocks trickling behind LDS-heavy GEMM blocks -> occ 21%, fat1 ~131us).
__global__ __launch_bounds__(256) void fat1_kernel(
    const float* __restrict__ x, const __hip_bfloat16* __restrict__ Wt0,
    __hip_bfloat16* __restrict__ T1, int Nn, int G1, int S,
    const int* __restrict__ e_dst, int* __restrict__ cnt, int* __restrict__ rank,
    int E, int CB,
    const float* __restrict__ W2, const float* __restrict__ W3, const float* __restrict__ W4,
    __hip_bfloat16* __restrict__ Tw2, __hip_bfloat16* __restrict__ Tw3,
    __hip_bfloat16* __restrict__ Tw4) {
  int b = (int)blockIdx.x;
  int inter = G1 * S;  // interleaved region size
  bool isGemm = (b < inter) && (b % S == 0);
  if (isGemm) {
    gemm_body<128, 1, 0>(x, Wt0, T1, nullptr, nullptr, nullptr, nullptr, nullptr,
                         nullptr, 0.f, Nn, 512, 128, b / S, 0);
    return;
  }
  int c = (b < inter) ? (b - b / S - 1) : (b - G1);
  if (c < CB) {
    int e = c * 256 + (int)threadIdx.x;
    if (e < E) rank[e] = atomicAdd(&cnt[e_dst[e]], 1);
  } else {
    int i = (c - CB) * 256 + (int)threadIdx.x;
    const float* W; __hip_bfloat16* T; int K, F, base;
    if (i < 32768)       { W = W2; T = Tw2; K = 128; F = 256; base = 0; }
    else if (i < 65536)  { W = W3; T = Tw3; K = 256; F = 128; base = 32768; }
    else if (i < 73728)  { W = W4; T = Tw4; K = 128; F = 64;  base = 65536; }
    else return;
    int j = i - base;
    int k = j / F, f = j % F;
    T[f * K + k] = __float2bfloat16(W[j]);
  }
}

template <int TN, int ASTAGE, int OMODE>
__global__ __launch_bounds__(256) void mfma_gemm_kernel(
    const void* __restrict__ A, const __hip_bfloat16* __restrict__ Bt,
    __hip_bfloat16* __restrict__ C, const float* __restrict__ bias,
    const float* __restrict__ rowscale, const float* __restrict__ statsIn,
    const float* __restrict__ g, const float* __restrict__ beta,
    float* __restrict__ statsOut, float invN, int Nr, int K, int F) {
  gemm_body<TN, ASTAGE, OMODE>(A, Bt, C, bias, rowscale, statsIn, g, beta, statsOut,
                               invN, Nr, K, F, (int)blockIdx.x, (int)blockIdx.y);
}

// ===== fat2: atomic-free scatter (rescale of T1 folded into agg L1) =====
__global__ __launch_bounds__(256) void fat2_kernel(
    const int* __restrict__ src, const int* __restrict__ dst,
    const int* __restrict__ rowstart, const int* __restrict__ rank,
    int* __restrict__ csr_src, int E) {
  int e = (int)blockIdx.x * 256 + (int)threadIdx.x;
  if (e < E) csr_src[rowstart[dst[e]] + rank[e]] = src[e];
}

// ================= aggregation (persistent grid-stride) =================
// Index/dis loads: ONE vector load by 16-lane groups + __shfl broadcast.
// AMODE 1 (L1): input UNSCALED T1; scale gathered rows by dis[src]; self by
//               dis[d]. H=dis*acc+bias; stats; R=bf16(relu(H)*dis); sd[d]
// AMODE 2 (L2 pre): input pre-scaled; out = bf16(dis*(ssc[c]*acc + ssb[c]*sd[d]))
// AMODE 3 (L3): input pre-scaled; H=dis*acc+bias; stats; R = bf16(relu(H))
// AMODE 4 (L4): input pre-scaled; H=dis*acc+bias; stats; R = fp32 relu(H)
template <int VEC, int AMODE>
__global__ __launch_bounds__(256) void agg_kernel(
    const __hip_bfloat16* __restrict__ Ts, const int* __restrict__ rowstart,
    const int* __restrict__ csr_src, const float* __restrict__ dis,
    const float* __restrict__ bias, void* __restrict__ H,
    float* __restrict__ stats, const float* __restrict__ statsIn,
    const float* __restrict__ g, const float* __restrict__ beta,
    float* __restrict__ sd, float invN, int Nn, int F) {
  __shared__ float lsum[512], lqs[512];
  __shared__ float ssc[128], ssb[128];
  int tid = (int)threadIdx.x;
  int wid4 = tid >> 6;
  int lane = tid & 63;
  int off = lane * VEC;
  const unsigned short* Tu = (const unsigned short*)Ts;

  if constexpr (AMODE == 2) {
    if (tid < F) {
      float mean = statsIn[tid] * invN;
      float var = statsIn[256 + tid] * invN - mean * mean;
      float sc = g[tid] * rsqrtf(var + EPS_BN);
      ssc[tid] = sc;
      ssb[tid] = beta[tid] - mean * sc;
    }
    __syncthreads();
  }

  float bj[VEC];
  float s[VEC], q[VEC];
#pragma unroll
  for (int j = 0; j < VEC; ++j) {
    bj[j] = (AMODE == 1 || AMODE == 3 || AMODE == 4) ? bias[off + j] : 0.f;
    s[j] = 0.f; q[j] = 0.f;
  }

  for (int d = blockIdx.x * 4 + wid4; d < Nn; d += gridDim.x * 4) {
    float dd = dis[d];
    float acc[VEC];
    {  // self term
      unsigned short r[VEC];
      if constexpr (VEC == 2) *(ushort2*)r = *(const ushort2*)&Tu[(size_t)d * F + off];
      else                    r[0] = Tu[(size_t)d * F + off];
#pragma unroll
      for (int j = 0; j < VEC; ++j) {
        if constexpr (AMODE == 1) acc[j] = bfu2f(r[j]) * dd;  // unscaled input
        else                      acc[j] = bfu2f(r[j]);       // pre-scaled input
      }
    }
    float sdacc = dd;

    int e0 = rowstart[d], e1 = rowstart[d + 1];
    for (int e = e0; e < e1; e += 16) {
      // cooperative index fetch: lanes p (mod 16) load csr_src[e+p], broadcast
      int ee = e + (lane & 15);
      if (ee >= e1) ee = e1 - 1;
      int myidx = csr_src[ee];
      float mydis = 0.f;
      if constexpr (AMODE == 1) mydis = dis[myidx];
      int idx[16];
      float dv[16];
#pragma unroll
      for (int p = 0; p < 16; ++p) {
        idx[p] = __shfl(myidx, p, 16);
        if constexpr (AMODE == 1) dv[p] = __shfl(mydis, p, 16);
      }
      unsigned short r[16][VEC];
#pragma unroll
      for (int p = 0; p < 16; ++p) {
        if constexpr (VEC == 2) *(ushort2*)r[p] = *(const ushort2*)&Tu[(size_t)idx[p] * F + off];
        else                    r[p][0] = Tu[(size_t)idx[p] * F + off];
      }
#pragma unroll
      for (int p = 0; p < 16; ++p) {
        bool val = (e + p) < e1;
        if constexpr (AMODE == 1) {
#pragma unroll
          for (int j = 0; j < VEC; ++j) acc[j] += val ? bfu2f(r[p][j]) * dv[p] : 0.f;
          sdacc += val ? dv[p] : 0.f;
        } else {
#pragma unroll
          for (int j = 0; j < VEC; ++j) acc[j] += val ? bfu2f(r[p][j]) : 0.f;
        }
      }
    }

    if constexpr (AMODE == 2) {
      float sdv = sd[d];
      union { ushort2 u; __hip_bfloat16 h[2]; } pk;
      pk.h[0] = __float2bfloat16(dd * (ssc[off + 0] * acc[0] + ssb[off + 0] * sdv));
      pk.h[1] = __float2bfloat16(dd * (ssc[off + 1] * acc[1] + ssb[off + 1] * sdv));
      *(ushort2*)&((__hip_bfloat16*)H)[(size_t)d * F + off] = pk.u;
    } else {
      float rl[VEC];
#pragma unroll
      for (int j = 0; j < VEC; ++j) {
        float v = acc[j] * dd + bj[j];
        rl[j] = fmaxf(v, 0.f);
        s[j] += rl[j];
        q[j] += rl[j] * rl[j];
      }
      if constexpr (AMODE == 1) {
        union { ushort2 u; __hip_bfloat16 h[2]; } pk;
        pk.h[0] = __float2bfloat16(rl[0] * dd);
        pk.h[1] = __float2bfloat16(rl[1] * dd);
        *(ushort2*)&((__hip_bfloat16*)H)[(size_t)d * F + off] = pk.u;
        if (lane == 0) sd[d] = sdacc;
      } else if constexpr (AMODE == 3) {
        union { ushort2 u; __hip_bfloat16 h[2]; } pk;
        pk.h[0] = __float2bfloat16(rl[0]);
        pk.h[1] = __float2bfloat16(rl[1]);
        *(ushort2*)&((__hip_bfloat16*)H)[(size_t)d * F + off] = pk.u;
      } else {  // AMODE 4, VEC==1, fp32 out
        ((float*)H)[(size_t)d * F + off] = rl[0];
      }
    }
  }

  if constexpr (AMODE != 2) {
#pragma unroll
    for (int j = 0; j < VEC; ++j) {
      lsum[(lane * VEC + j) * 4 + wid4] = s[j];
      lqs[(lane * VEC + j) * 4 + wid4] = q[j];
    }
    __syncthreads();
    int nc = 64 * VEC;  // == F
    for (int c = tid; c < nc; c += 256) {
      float a = lsum[c * 4 + 0] + lsum[c * 4 + 1] + lsum[c * 4 + 2] + lsum[c * 4 + 3];
      float b = lqs[c * 4 + 0] + lqs[c * 4 + 1] + lqs[c * 4 + 2] + lqs[c * 4 + 3];
      atomicAdd(&stats[c], a);
      atomicAdd(&stats[256 + c], b);
    }
  }
}

// ================= fused L4 BN-apply + classifier =================
// input R4 already relu'd (fp32); one wave per row.
__global__ __launch_bounds__(256) void bnapply_cls_kernel(
    const float* __restrict__ R4, const float* __restrict__ stats,
    const float* __restrict__ g, const float* __restrict__ beta,
    const float* __restrict__ Wc, const float* __restrict__ bc,
    float* __restrict__ out, int Nn, float invN) {
  __shared__ float ssc[64], ssb[64];
  int tid = (int)threadIdx.x;
  if (tid < 64) {
    float mean = stats[tid] * invN;
    float var = stats[256 + tid] * invN - mean * mean;
    float sc = g[tid] * rsqrtf(var + EPS_BN);
    ssc[tid] = sc;
    ssb[tid] = beta[tid] - mean * sc;
  }
  __syncthreads();
  int gt = blockIdx.x * blockDim.x + tid;
  int wid = gt >> 6;
  int lane = tid & 63;
  if (wid >= Nn) return;
  float v = R4[(size_t)wid * 64 + lane];
  float h = v * ssc[lane] + ssb[lane];
#pragma unroll
  for (int c = 0; c < 10; ++c) {
    float p = h * Wc[lane * 10 + c];
#pragma unroll
    for (int off = 32; off > 0; off >>= 1) p += __shfl_down(p, off, 64);
    if (lane == 0) out[(size_t)wid * 10 + c] = p + bc[c];
  }
}

// ================= host launch =================

extern "C" void kernel_launch(void* const* d_in, const int* in_sizes, int n_in,
                              void* d_out, int out_size, void* d_ws, size_t ws_size,
                              hipStream_t stream) {
  (void)n_in; (void)out_size; (void)ws_size;
  const float* x    = (const float*)d_in[0];
  const int*   edge = (const int*)d_in[1];
  const int E  = in_sizes[1] / 2;
  const int Nn = in_sizes[0] / 512;
  const int* e_src = edge;
  const int* e_dst = edge + E;

  const float* W[4]  = {(const float*)d_in[2],  (const float*)d_in[6],
                        (const float*)d_in[10], (const float*)d_in[14]};
  const float* bv[4] = {(const float*)d_in[3],  (const float*)d_in[7],
                        (const float*)d_in[11], (const float*)d_in[15]};
  const float* gv[4] = {(const float*)d_in[4],  (const float*)d_in[8],
                        (const float*)d_in[12], (const float*)d_in[16]};
  const float* bt[4] = {(const float*)d_in[5],  (const float*)d_in[9],
                        (const float*)d_in[13], (const float*)d_in[17]};
  const float* Wc = (const float*)d_in[18];
  const float* bc = (const float*)d_in[19];
  float* out = (float*)d_out;

  const float invN = 1.0f / (float)Nn;

  char* p = (char*)d_ws;
  auto alloc = [&](size_t bytes) -> void* {
    void* r = (void*)p;
    p += (bytes + 255) & ~(size_t)255;
    return r;
  };
  // cnt + stats adjacent -> single memset covers both
  int*   cnt      = (int*)alloc((size_t)Nn * 4);
  float* stats    = (float*)alloc(2048 * 4);   // L1 | L2 | L3 | L4, each 512
  size_t zeroBytes = (size_t)(((size_t)Nn * 4 + 255) & ~(size_t)255) + 2048 * 4;
  int*   rowstart = (int*)alloc((size_t)(Nn + 1) * 4);
  int*   bsum     = (int*)alloc(1024 * 4);
  float* dis      = (float*)alloc((size_t)Nn * 4);
  float* sd       = (float*)alloc((size_t)Nn * 4);
  int*   rank     = (int*)alloc((size_t)E * 4);
  int*   csr_src  = (int*)alloc((size_t)E * 4);
  __hip_bfloat16* Wt0 = (__hip_bfloat16*)alloc(512 * 128 * 2);
  __hip_bfloat16* Wt1 = (__hip_bfloat16*)alloc(128 * 256 * 2);
  __hip_bfloat16* Wt2 = (__hip_bfloat16*)alloc(256 * 128 * 2);
  __hip_bfloat16* Wt3 = (__hip_bfloat16*)alloc(128 * 64 * 2);
  __hip_bfloat16* Ts1 = (__hip_bfloat16*)alloc((size_t)Nn * 128 * 2);
  __hip_bfloat16* R1  = (__hip_bfloat16*)alloc((size_t)Nn * 128 * 2);
  __hip_bfloat16* Tb2 = (__hip_bfloat16*)alloc((size_t)Nn * 128 * 2);
  __hip_bfloat16* R2  = (__hip_bfloat16*)alloc((size_t)Nn * 256 * 2);
  __hip_bfloat16* Ts3 = (__hip_bfloat16*)alloc((size_t)Nn * 128 * 2);
  __hip_bfloat16* R3  = (__hip_bfloat16*)alloc((size_t)Nn * 128 * 2);
  __hip_bfloat16* Ts4 = (__hip_bfloat16*)alloc((size_t)Nn * 64 * 2);
  float*          R4  = (float*)alloc((size_t)Nn * 64 * 4);

  hipMemsetAsync(cnt, 0, zeroBytes, stream);

  // Wt0 first (fat1's GEMM B operand)
  wtrans1_kernel<<<(512 * 128 + 255) / 256, 256, 0, stream>>>(W[0], Wt0);

  // ---- fat1: GEMM1 || count || wtrans, roles interleaved with stride S
  const int gx = (Nn + 127) / 128;
  const int CB = (E + 255) / 256;
  const int WB = (73728 + 255) / 256;
  const int S  = 1 + (CB + WB) / gx;  // every S-th block is a GEMM block
  fat1_kernel<<<gx + CB + WB, 256, 0, stream>>>(
      x, Wt0, Ts1, Nn, gx, S, e_dst, cnt, rank, E, CB,
      W[1], W[2], W[3], Wt1, Wt2, Wt3);

  int nb = (Nn + 1023) / 1024;
  scan1_kernel<<<nb, 1024, 0, stream>>>(cnt, rowstart, bsum, dis, Nn);
  scan2_kernel<<<1, 1024, 0, stream>>>(bsum, nb);
  scan3_kernel<<<nb, 1024, 0, stream>>>(rowstart, bsum, Nn, E);

  // ---- fat2: scatter only (T1 stays unscaled; agg L1 folds dis)
  fat2_kernel<<<CB, 256, 0, stream>>>(e_src, e_dst, rowstart, rank, csr_src, E);

  const int AGG_BLOCKS = 2048;

  // ---- L1: agg(T1 unscaled) -> R1 = relu(H1)*dis bf16, stats0, sd
  agg_kernel<2, 1><<<AGG_BLOCKS, 256, 0, stream>>>(
      Ts1, rowstart, csr_src, dis, bv[0], R1, stats, nullptr, nullptr, nullptr,
      sd, invN, Nn, 128);
  // ---- L2 pre-agg: agg(R1) -> Tb2 (BN1 folded)
  agg_kernel<2, 2><<<AGG_BLOCKS, 256, 0, stream>>>(
      R1, rowstart, csr_src, dis, nullptr, Tb2, nullptr, stats, gv[0], bt[0],
      sd, invN, Nn, 128);
  // ---- GEMM2: Tb2[128] -> R2 = relu(H2) bf16 [256], stats1
  {
    dim3 g(gx, 2);
    mfma_gemm_kernel<128, 0, 3><<<g, 256, 0, stream>>>(
        Tb2, Wt1, R2, bv[1], nullptr, nullptr, nullptr, nullptr, stats + 512, invN,
        Nn, 128, 256);
  }
  // ---- GEMM3: A = BN2(R2) via affine staging -> Ts3 = out*dis bf16 [128]
  {
    dim3 g(gx, 1);
    mfma_gemm_kernel<128, 2, 1><<<g, 256, 0, stream>>>(
        R2, Wt2, Ts3, nullptr, dis, stats + 512, gv[1], bt[1], nullptr, invN,
        Nn, 256, 128);
  }
  // ---- L3: agg(Ts3) -> R3 = relu(H3) bf16, stats2
  agg_kernel<2, 3><<<AGG_BLOCKS, 256, 0, stream>>>(
      Ts3, rowstart, csr_src, dis, bv[2], R3, stats + 1024, nullptr, nullptr, nullptr,
      nullptr, invN, Nn, 128);
  // ---- GEMM4: A = BN3(R3) via affine staging -> Ts4 = out*dis bf16 [64]
  {
    dim3 g(gx, 1);
    mfma_gemm_kernel<64, 2, 1><<<g, 256, 0, stream>>>(
        R3, Wt3, Ts4, nullptr, dis, stats + 1024, gv[2], bt[2], nullptr, invN,
        Nn, 128, 64);
  }
  // ---- L4: agg(Ts4) -> R4 = relu(H4) fp32, stats3
  agg_kernel<1, 4><<<AGG_BLOCKS, 256, 0, stream>>>(
      Ts4, rowstart, csr_src, dis, bv[3], R4, stats + 1536, nullptr, nullptr, nullptr,
      nullptr, invN, Nn, 64);
  // ---- BN4 + classifier
  int clsBlocks = (Nn * 64 + 255) / 256;
  bnapply_cls_kernel<<<clsBlocks, 256, 0, stream>>>(R4, stats + 1536, gv[3], bt[3],
                                                    Wc, bc, out, Nn, invN);
}